// Round 1
// baseline (253.972 us; speedup 1.0000x reference)
//
#include <hip/hip_runtime.h>
#include <hip/hip_bf16.h>
#include <stdint.h>

// RecurrentReadout: x[16,256,1024,8,8] -> spatial mean -> linear (W[1024,1024],b) -> diag recurrence over T.
// Pipeline: k_wcvt (W->bf16) ; k_mean (1GiB read, BW-bound floor) ; k_gemm (bf16 MFMA, u -> d_out r_seq region) ;
//           k_scan (in-place recurrence over T, writes r_seq + r_final).

typedef __attribute__((ext_vector_type(8))) short bf16x8;   // 8 bf16 = 4 VGPRs (MFMA A/B frag)
typedef __attribute__((ext_vector_type(4))) float f32x4;    // MFMA C/D frag

__device__ __forceinline__ unsigned short f2bf(float f) {
  union { float f; unsigned int u; } c; c.f = f;
  unsigned int u = c.u;
  return (unsigned short)((u + 0x7FFFu + ((u >> 16) & 1u)) >> 16);  // RNE
}

// ---------------- W fp32 -> bf16 ----------------
__global__ __launch_bounds__(256) void k_wcvt(const float* __restrict__ W,
                                              unsigned short* __restrict__ Wb) {
  int i = (blockIdx.x * 256 + threadIdx.x) * 4;
  float4 v = *(const float4*)(W + i);
  ushort4 o;
  o.x = f2bf(v.x); o.y = f2bf(v.y); o.z = f2bf(v.z); o.w = f2bf(v.w);
  *(ushort4*)(Wb + i) = o;
}

// ---------------- spatial mean: x[seg][64] -> xm[seg] (bf16) ----------------
// 16 lanes per segment, float4 each (coalesced 4KB/block/iter). shfl_xor tree within 16-lane groups.
__global__ __launch_bounds__(256) void k_mean(const float* __restrict__ x,
                                              unsigned short* __restrict__ xm) {
  const int tid = threadIdx.x;
  const int sub = tid & 15;
  const int grp = tid >> 4;
  for (int base = blockIdx.x * 16; base < (1 << 22); base += gridDim.x * 16) {
    int seg = base + grp;
    const float4 v = *(const float4*)(x + (long)seg * 64 + sub * 4);
    float s = v.x + v.y + v.z + v.w;
    s += __shfl_xor(s, 1);
    s += __shfl_xor(s, 2);
    s += __shfl_xor(s, 4);
    s += __shfl_xor(s, 8);
    if (sub == 0) xm[seg] = f2bf(s * 0.015625f);
  }
}

// ---------------- bf16 GEMM: U[4096,1024] = xm[4096,1024] * Wb[1024,1024]^T ----------------
// 128x128 tile, BK=32, 4 waves (2x2), 4x4 16x16x32 frags/wave. global_load_lds width=16.
// LDS XOR-swizzle: physical slot = logical_kslot ^ (row&3) -> 2-way bank conflict (free).
// global_load_lds writes linearly, so the swizzle is applied on the GLOBAL source address.
#define GLDS16(g, l) \
  __builtin_amdgcn_global_load_lds((const __attribute__((address_space(1))) void*)(g), \
                                   (__attribute__((address_space(3))) void*)(l), 16, 0, 0)

__global__ __launch_bounds__(256) void k_gemm(const unsigned short* __restrict__ A,
                                              const unsigned short* __restrict__ Bm,
                                              float* __restrict__ U) {
  __shared__ unsigned short As[128 * 32];  // 8 KiB
  __shared__ unsigned short Bs[128 * 32];  // 8 KiB
  const int tid  = threadIdx.x;
  const int lane = tid & 63;
  const int wid  = tid >> 6;
  const int wr = wid >> 1, wc = wid & 1;
  const int m0 = blockIdx.y * 128, n0 = blockIdx.x * 128;

  f32x4 acc[4][4] = {};

  const int srow  = tid >> 2;  // staging row 0..63 (+64 in round 1)
  const int sslot = tid & 3;   // physical 16B slot within 64B row
  const int r16   = lane & 15;
  const int kb    = lane >> 4;

  for (int k0 = 0; k0 < 1024; k0 += 32) {
#pragma unroll
    for (int rnd = 0; rnd < 2; rnd++) {
      const int r  = srow + rnd * 64;
      const int gk = (sslot ^ (r & 3)) << 3;  // pre-swizzled global k-offset (elements)
      GLDS16(A  + (long)(m0 + r) * 1024 + k0 + gk, (char*)As + tid * 16 + rnd * 4096);
      GLDS16(Bm + (long)(n0 + r) * 1024 + k0 + gk, (char*)Bs + tid * 16 + rnd * 4096);
    }
    __syncthreads();  // compiler drains vmcnt before s_barrier

    bf16x8 af[4], bfr[4];
#pragma unroll
    for (int i = 0; i < 4; i++) {
      const int rr = wr * 64 + i * 16 + r16;
      af[i] = *(const bf16x8*)(As + rr * 32 + ((kb ^ (rr & 3)) << 3));
    }
#pragma unroll
    for (int j = 0; j < 4; j++) {
      const int cc = wc * 64 + j * 16 + r16;
      bfr[j] = *(const bf16x8*)(Bs + cc * 32 + ((kb ^ (cc & 3)) << 3));
    }
#pragma unroll
    for (int i = 0; i < 4; i++)
#pragma unroll
      for (int j = 0; j < 4; j++)
        acc[i][j] = __builtin_amdgcn_mfma_f32_16x16x32_bf16(af[i], bfr[j], acc[i][j], 0, 0, 0);
    __syncthreads();
  }

  // C/D layout: col = lane&15, row = (lane>>4)*4 + reg  [measured m89/m91]
  const int orow = (lane >> 4) * 4;
  const int ocol = lane & 15;
#pragma unroll
  for (int i = 0; i < 4; i++)
#pragma unroll
    for (int j = 0; j < 4; j++) {
      const int m = m0 + wr * 64 + i * 16 + orow;
      const int n = n0 + wc * 64 + j * 16 + ocol;
#pragma unroll
      for (int q = 0; q < 4; q++)
        U[(long)(m + q) * 1024 + n] = acc[i][j][q];
    }
}

// ---------------- diag recurrence over T, in-place in d_out ----------------
// r_t = alpha*r_{t-1} + (u_t + b); r_seq overwrites u; r_final appended after r_seq.
__global__ __launch_bounds__(256) void k_scan(const float* __restrict__ r0,
                                              const float* __restrict__ bias,
                                              const float* __restrict__ alpha,
                                              float* __restrict__ out) {
  const int gid = blockIdx.x * 256 + threadIdx.x;  // 0..16383 = b*1024 + o
  const int o = gid & 1023;
  const float a  = alpha[o];
  const float bb = bias[o];
  float r = r0[gid];
  const long base = (long)(gid >> 10) * (256L * 1024) + o;
#pragma unroll 8
  for (int t = 0; t < 256; t++) {
    const float u = out[base + t * 1024];
    r = fmaf(a, r, u + bb);
    out[base + t * 1024] = r;
  }
  out[(1 << 22) + gid] = r;  // r_final
}

extern "C" void kernel_launch(void* const* d_in, const int* in_sizes, int n_in,
                              void* d_out, int out_size, void* d_ws, size_t ws_size,
                              hipStream_t stream) {
  const float* x     = (const float*)d_in[0];
  const float* r0    = (const float*)d_in[1];
  const float* W     = (const float*)d_in[2];
  const float* b     = (const float*)d_in[3];
  const float* alpha = (const float*)d_in[4];
  float* out = (float*)d_out;

  unsigned short* xm = (unsigned short*)d_ws;                        // 8 MiB: [4096][1024] bf16
  unsigned short* Wb = (unsigned short*)((char*)d_ws + (8u << 20));  // 2 MiB: [1024][1024] bf16

  k_wcvt<<<1024, 256, 0, stream>>>(W, Wb);
  k_mean<<<2048, 256, 0, stream>>>(x, xm);
  dim3 g(8, 32);  // x: N-tiles (1024/128), y: M-tiles (4096/128)
  k_gemm<<<g, 256, 0, stream>>>(xm, Wb, out);
  k_scan<<<64, 256, 0, stream>>>(r0, b, alpha, out);
}

// Round 2
// 246.921 us; speedup vs baseline: 1.0286x; 1.0286x over previous
//
#include <hip/hip_runtime.h>
#include <hip/hip_bf16.h>
#include <stdint.h>

// RecurrentReadout: x[16,256,1024,8,8] -> spatial mean -> linear (W[1024,1024],b) -> diag recurrence over T.
// Pipeline: k_wcvt (W->bf16) ; k_mean (1GiB read, BW-bound floor ~170us) ; k_gemm (bf16 MFMA, u -> d_out) ;
//           k_scan (in-place recurrence, 64-deep load batching for latency hiding at 1 wave/CU).

typedef __attribute__((ext_vector_type(8))) short bf16x8;   // 8 bf16 = 4 VGPRs (MFMA A/B frag)
typedef __attribute__((ext_vector_type(4))) float f32x4;    // MFMA C/D frag

__device__ __forceinline__ unsigned short f2bf(float f) {
  union { float f; unsigned int u; } c; c.f = f;
  unsigned int u = c.u;
  return (unsigned short)((u + 0x7FFFu + ((u >> 16) & 1u)) >> 16);  // RNE
}

// ---------------- W fp32 -> bf16 ----------------
__global__ __launch_bounds__(256) void k_wcvt(const float* __restrict__ W,
                                              unsigned short* __restrict__ Wb) {
  int i = (blockIdx.x * 256 + threadIdx.x) * 4;
  float4 v = *(const float4*)(W + i);
  ushort4 o;
  o.x = f2bf(v.x); o.y = f2bf(v.y); o.z = f2bf(v.z); o.w = f2bf(v.w);
  *(ushort4*)(Wb + i) = o;
}

// ---------------- spatial mean: x[seg][64] -> xm[seg] (bf16) ----------------
// 16 lanes per segment, float4 each (4KB contiguous per block-iter). shfl_xor tree in 16-lane groups.
__global__ __launch_bounds__(256) void k_mean(const float* __restrict__ x,
                                              unsigned short* __restrict__ xm) {
  const int tid = threadIdx.x;
  const int sub = tid & 15;
  const int grp = tid >> 4;
  for (int base = blockIdx.x * 16; base < (1 << 22); base += gridDim.x * 16) {
    int seg = base + grp;
    const float4 v = *(const float4*)(x + (long)seg * 64 + sub * 4);
    float s = v.x + v.y + v.z + v.w;
    s += __shfl_xor(s, 1);
    s += __shfl_xor(s, 2);
    s += __shfl_xor(s, 4);
    s += __shfl_xor(s, 8);
    if (sub == 0) xm[seg] = f2bf(s * 0.015625f);
  }
}

// ---------------- bf16 GEMM: U[4096,1024] = xm[4096,1024] * Wb[1024,1024]^T ----------------
// 128x128 tile, BK=32, 4 waves (2x2), 4x4 16x16x32 frags/wave. global_load_lds width=16.
// LDS XOR-swizzle: physical slot = logical_kslot ^ (row&3) -> 2-way conflict (free).
// global_load_lds writes linearly, so the swizzle is applied on the GLOBAL source address.
#define GLDS16(g, l) \
  __builtin_amdgcn_global_load_lds((const __attribute__((address_space(1))) void*)(g), \
                                   (__attribute__((address_space(3))) void*)(l), 16, 0, 0)

__global__ __launch_bounds__(256) void k_gemm(const unsigned short* __restrict__ A,
                                              const unsigned short* __restrict__ Bm,
                                              float* __restrict__ U) {
  __shared__ unsigned short As[128 * 32];  // 8 KiB
  __shared__ unsigned short Bs[128 * 32];  // 8 KiB
  const int tid  = threadIdx.x;
  const int lane = tid & 63;
  const int wid  = tid >> 6;
  const int wr = wid >> 1, wc = wid & 1;
  const int m0 = blockIdx.y * 128, n0 = blockIdx.x * 128;

  f32x4 acc[4][4] = {};

  const int srow  = tid >> 2;  // staging row 0..63 (+64 in round 1)
  const int sslot = tid & 3;   // physical 16B slot within 64B row
  const int r16   = lane & 15;
  const int kb    = lane >> 4;

  for (int k0 = 0; k0 < 1024; k0 += 32) {
#pragma unroll
    for (int rnd = 0; rnd < 2; rnd++) {
      const int r  = srow + rnd * 64;
      const int gk = (sslot ^ (r & 3)) << 3;  // pre-swizzled global k-offset (elements)
      GLDS16(A  + (long)(m0 + r) * 1024 + k0 + gk, (char*)As + tid * 16 + rnd * 4096);
      GLDS16(Bm + (long)(n0 + r) * 1024 + k0 + gk, (char*)Bs + tid * 16 + rnd * 4096);
    }
    __syncthreads();  // compiler drains vmcnt before s_barrier

    bf16x8 af[4], bfr[4];
#pragma unroll
    for (int i = 0; i < 4; i++) {
      const int rr = wr * 64 + i * 16 + r16;
      af[i] = *(const bf16x8*)(As + rr * 32 + ((kb ^ (rr & 3)) << 3));
    }
#pragma unroll
    for (int j = 0; j < 4; j++) {
      const int cc = wc * 64 + j * 16 + r16;
      bfr[j] = *(const bf16x8*)(Bs + cc * 32 + ((kb ^ (cc & 3)) << 3));
    }
#pragma unroll
    for (int i = 0; i < 4; i++)
#pragma unroll
      for (int j = 0; j < 4; j++)
        acc[i][j] = __builtin_amdgcn_mfma_f32_16x16x32_bf16(af[i], bfr[j], acc[i][j], 0, 0, 0);
    __syncthreads();
  }

  // C/D layout: col = lane&15, row = (lane>>4)*4 + reg  [measured m89/m91]
  const int orow = (lane >> 4) * 4;
  const int ocol = lane & 15;
#pragma unroll
  for (int i = 0; i < 4; i++)
#pragma unroll
    for (int j = 0; j < 4; j++) {
      const int m = m0 + wr * 64 + i * 16 + orow;
      const int n = n0 + wc * 64 + j * 16 + ocol;
#pragma unroll
      for (int q = 0; q < 4; q++)
        U[(long)(m + q) * 1024 + n] = acc[i][j][q];
    }
}

// ---------------- diag recurrence over T, in-place in d_out ----------------
// r_t = alpha*r_{t-1} + (u_t + b); r_seq overwrites u; r_final appended after r_seq.
// 1 wave/CU (only 16384 (b,o) pairs) -> latency-bound. Batch loads 64-deep: issue 64
// independent global loads before any use (all addrs independent of the FMA chain),
// then run the dependence chain on registers, then 64 stores. Static indexing only
// (full unroll) so buf[] stays in VGPRs (rule #20).
__global__ __launch_bounds__(256) void k_scan(const float* __restrict__ r0,
                                              const float* __restrict__ bias,
                                              const float* __restrict__ alpha,
                                              float* __restrict__ out) {
  const int gid = blockIdx.x * 256 + threadIdx.x;  // 0..16383 = b*1024 + o
  const int o = gid & 1023;
  const float a  = alpha[o];
  const float bb = bias[o];
  float r = r0[gid];
  float* p = out + (long)(gid >> 10) * (256L * 1024) + o;
#pragma unroll 1
  for (int g = 0; g < 4; g++) {
    float buf[64];
#pragma unroll
    for (int i = 0; i < 64; i++) buf[i] = p[i * 1024];
#pragma unroll
    for (int i = 0; i < 64; i++) { r = fmaf(a, r, buf[i] + bb); buf[i] = r; }
#pragma unroll
    for (int i = 0; i < 64; i++) p[i * 1024] = buf[i];
    p += 64 * 1024;
  }
  out[(1 << 22) + gid] = r;  // r_final
}

extern "C" void kernel_launch(void* const* d_in, const int* in_sizes, int n_in,
                              void* d_out, int out_size, void* d_ws, size_t ws_size,
                              hipStream_t stream) {
  const float* x     = (const float*)d_in[0];
  const float* r0    = (const float*)d_in[1];
  const float* W     = (const float*)d_in[2];
  const float* b     = (const float*)d_in[3];
  const float* alpha = (const float*)d_in[4];
  float* out = (float*)d_out;

  unsigned short* xm = (unsigned short*)d_ws;                        // 8 MiB: [4096][1024] bf16
  unsigned short* Wb = (unsigned short*)((char*)d_ws + (8u << 20));  // 2 MiB: [1024][1024] bf16

  k_wcvt<<<1024, 256, 0, stream>>>(W, Wb);
  k_mean<<<2048, 256, 0, stream>>>(x, xm);
  dim3 g(8, 32);  // x: N-tiles (1024/128), y: M-tiles (4096/128)
  k_gemm<<<g, 256, 0, stream>>>(xm, Wb, out);
  k_scan<<<64, 256, 0, stream>>>(r0, b, alpha, out);
}

// Round 3
// 237.759 us; speedup vs baseline: 1.0682x; 1.0385x over previous
//
#include <hip/hip_runtime.h>
#include <hip/hip_bf16.h>
#include <stdint.h>

// RecurrentReadout: x[16,256,1024,8,8] -> spatial mean -> linear (W[1024,1024],b) -> diag recurrence over T.
// Pipeline: k_wcvt (W->bf16) ; k_mean (1GiB read, BW floor ~165us) ; k_gemm 64x64 tiles (1024 blocks = 4/CU) ;
//           k_scan (in-place recurrence, 64-deep load batching).

typedef __attribute__((ext_vector_type(8))) short bf16x8;   // 8 bf16 = 4 VGPRs (MFMA A/B frag)
typedef __attribute__((ext_vector_type(4))) float f32x4;    // MFMA C/D frag

__device__ __forceinline__ unsigned short f2bf(float f) {
  union { float f; unsigned int u; } c; c.f = f;
  unsigned int u = c.u;
  return (unsigned short)((u + 0x7FFFu + ((u >> 16) & 1u)) >> 16);  // RNE
}

// ---------------- W fp32 -> bf16 ----------------
__global__ __launch_bounds__(256) void k_wcvt(const float* __restrict__ W,
                                              unsigned short* __restrict__ Wb) {
  int i = (blockIdx.x * 256 + threadIdx.x) * 4;
  float4 v = *(const float4*)(W + i);
  ushort4 o;
  o.x = f2bf(v.x); o.y = f2bf(v.y); o.z = f2bf(v.z); o.w = f2bf(v.w);
  *(ushort4*)(Wb + i) = o;
}

// ---------------- spatial mean: x[seg][64] -> xm[seg] (bf16) ----------------
// 16 lanes per segment, float4 each (4KB contiguous per block-iter). shfl_xor tree in 16-lane groups.
__global__ __launch_bounds__(256) void k_mean(const float* __restrict__ x,
                                              unsigned short* __restrict__ xm) {
  const int tid = threadIdx.x;
  const int sub = tid & 15;
  const int grp = tid >> 4;
  for (int base = blockIdx.x * 16; base < (1 << 22); base += gridDim.x * 16) {
    int seg = base + grp;
    const float4 v = *(const float4*)(x + (long)seg * 64 + sub * 4);
    float s = v.x + v.y + v.z + v.w;
    s += __shfl_xor(s, 1);
    s += __shfl_xor(s, 2);
    s += __shfl_xor(s, 4);
    s += __shfl_xor(s, 8);
    if (sub == 0) xm[seg] = f2bf(s * 0.015625f);
  }
}

// ---------------- bf16 GEMM: U[4096,1024] = xm[4096,1024] * Wb[1024,1024]^T ----------------
// 64x64 tile, BK=32, 4 waves (2x2 of 32x32), 2x2 16x16x32 frags/wave. Grid 64x16 = 1024
// blocks = 4 blocks/CU (16 waves/CU) so inter-wave overlap hides the vmcnt drain that
// exposed itself at 1 block/CU with 128^2 tiles. global_load_lds width=16, one round per
// operand per k-step. LDS XOR-swizzle (slot ^= row&3): applied on the GLOBAL source addr
// (global_load_lds dest must be linear) and identically on the ds_read side.
#define GLDS16(g, l) \
  __builtin_amdgcn_global_load_lds((const __attribute__((address_space(1))) void*)(g), \
                                   (__attribute__((address_space(3))) void*)(l), 16, 0, 0)

__global__ __launch_bounds__(256) void k_gemm(const unsigned short* __restrict__ A,
                                              const unsigned short* __restrict__ Bm,
                                              float* __restrict__ U) {
  __shared__ unsigned short As[64 * 32];  // 4 KiB
  __shared__ unsigned short Bs[64 * 32];  // 4 KiB
  const int tid  = threadIdx.x;
  const int lane = tid & 63;
  const int wid  = tid >> 6;
  const int wr = wid >> 1, wc = wid & 1;
  const int m0 = blockIdx.y * 64, n0 = blockIdx.x * 64;

  f32x4 acc[2][2] = {};

  const int srow  = tid >> 2;  // staging row 0..63
  const int sslot = tid & 3;   // physical 16B slot within 64B row
  const int gk0   = (sslot ^ (srow & 3)) << 3;  // pre-swizzled global k-offset (elements)
  const int r16   = lane & 15;
  const int kb    = lane >> 4;

  const unsigned short* ag = A  + (long)(m0 + srow) * 1024 + gk0;
  const unsigned short* bg = Bm + (long)(n0 + srow) * 1024 + gk0;

  for (int k0 = 0; k0 < 1024; k0 += 32) {
    GLDS16(ag + k0, (char*)As + tid * 16);
    GLDS16(bg + k0, (char*)Bs + tid * 16);
    __syncthreads();  // compiler drains vmcnt before s_barrier

    bf16x8 af[2], bfr[2];
#pragma unroll
    for (int i = 0; i < 2; i++) {
      const int rr = wr * 32 + i * 16 + r16;
      af[i] = *(const bf16x8*)(As + rr * 32 + ((kb ^ (rr & 3)) << 3));
    }
#pragma unroll
    for (int j = 0; j < 2; j++) {
      const int cc = wc * 32 + j * 16 + r16;
      bfr[j] = *(const bf16x8*)(Bs + cc * 32 + ((kb ^ (cc & 3)) << 3));
    }
#pragma unroll
    for (int i = 0; i < 2; i++)
#pragma unroll
      for (int j = 0; j < 2; j++)
        acc[i][j] = __builtin_amdgcn_mfma_f32_16x16x32_bf16(af[i], bfr[j], acc[i][j], 0, 0, 0);
    __syncthreads();
  }

  // C/D layout: col = lane&15, row = (lane>>4)*4 + reg  [measured m89/m91]
  const int orow = (lane >> 4) * 4;
  const int ocol = lane & 15;
#pragma unroll
  for (int i = 0; i < 2; i++)
#pragma unroll
    for (int j = 0; j < 2; j++) {
      const int m = m0 + wr * 32 + i * 16 + orow;
      const int n = n0 + wc * 32 + j * 16 + ocol;
#pragma unroll
      for (int q = 0; q < 4; q++)
        U[(long)(m + q) * 1024 + n] = acc[i][j][q];
    }
}

// ---------------- diag recurrence over T, in-place in d_out ----------------
// r_t = alpha*r_{t-1} + (u_t + b); r_seq overwrites u; r_final appended after r_seq.
// 1 wave/CU (16384 (b,o) pairs) -> latency-bound; batch loads 64-deep (static indexing
// only, rule #20, so buf[] stays in VGPRs).
__global__ __launch_bounds__(256) void k_scan(const float* __restrict__ r0,
                                              const float* __restrict__ bias,
                                              const float* __restrict__ alpha,
                                              float* __restrict__ out) {
  const int gid = blockIdx.x * 256 + threadIdx.x;  // 0..16383 = b*1024 + o
  const int o = gid & 1023;
  const float a  = alpha[o];
  const float bb = bias[o];
  float r = r0[gid];
  float* p = out + (long)(gid >> 10) * (256L * 1024) + o;
#pragma unroll 1
  for (int g = 0; g < 4; g++) {
    float buf[64];
#pragma unroll
    for (int i = 0; i < 64; i++) buf[i] = p[i * 1024];
#pragma unroll
    for (int i = 0; i < 64; i++) { r = fmaf(a, r, buf[i] + bb); buf[i] = r; }
#pragma unroll
    for (int i = 0; i < 64; i++) p[i * 1024] = buf[i];
    p += 64 * 1024;
  }
  out[(1 << 22) + gid] = r;  // r_final
}

extern "C" void kernel_launch(void* const* d_in, const int* in_sizes, int n_in,
                              void* d_out, int out_size, void* d_ws, size_t ws_size,
                              hipStream_t stream) {
  const float* x     = (const float*)d_in[0];
  const float* r0    = (const float*)d_in[1];
  const float* W     = (const float*)d_in[2];
  const float* b     = (const float*)d_in[3];
  const float* alpha = (const float*)d_in[4];
  float* out = (float*)d_out;

  unsigned short* xm = (unsigned short*)d_ws;                        // 8 MiB: [4096][1024] bf16
  unsigned short* Wb = (unsigned short*)((char*)d_ws + (8u << 20));  // 2 MiB: [1024][1024] bf16

  k_wcvt<<<1024, 256, 0, stream>>>(W, Wb);
  k_mean<<<2048, 256, 0, stream>>>(x, xm);
  dim3 g(16, 64);  // x: N-tiles (1024/64), y: M-tiles (4096/64)
  k_gemm<<<g, 256, 0, stream>>>(xm, Wb, out);
  k_scan<<<64, 256, 0, stream>>>(r0, b, alpha, out);
}

// Round 4
// 235.516 us; speedup vs baseline: 1.0784x; 1.0095x over previous
//
#include <hip/hip_runtime.h>
#include <hip/hip_bf16.h>
#include <stdint.h>

// RecurrentReadout: x[16,256,1024,8,8] -> spatial mean -> linear (W[1024,1024],b) -> diag recurrence over T.
// 3 kernels: k_mean (1GiB read BW floor, + embedded W->bf16 cvt) ; k_gemm 128x64 tiles (512 blocks, 2/CU,
// 2-way-free LDS swizzle, bias fused in epilogue) ; k_scan (software-pipelined in-place recurrence).

typedef __attribute__((ext_vector_type(8))) short bf16x8;   // 8 bf16 = 4 VGPRs (MFMA A/B frag)
typedef __attribute__((ext_vector_type(4))) float f32x4;    // MFMA C/D frag

__device__ __forceinline__ unsigned short f2bf(float f) {
  union { float f; unsigned int u; } c; c.f = f;
  unsigned int u = c.u;
  return (unsigned short)((u + 0x7FFFu + ((u >> 16) & 1u)) >> 16);  // RNE
}

// ---------------- spatial mean (+ W fp32->bf16 piggybacked) ----------------
// 16 lanes per segment, float4 each (4KB contiguous per block-iter). shfl_xor tree in 16-lane groups.
__global__ __launch_bounds__(256) void k_mean(const float* __restrict__ x,
                                              unsigned short* __restrict__ xm,
                                              const float* __restrict__ W,
                                              unsigned short* __restrict__ Wb) {
  const int tid = threadIdx.x;
  // piggyback: first 262144 threads convert one float4 of W (1M elems total)
  const int wi = blockIdx.x * 256 + tid;
  if (wi < 262144) {
    float4 v = *(const float4*)(W + wi * 4);
    ushort4 o;
    o.x = f2bf(v.x); o.y = f2bf(v.y); o.z = f2bf(v.z); o.w = f2bf(v.w);
    *(ushort4*)(Wb + wi * 4) = o;
  }
  const int sub = tid & 15;
  const int grp = tid >> 4;
  for (int base = blockIdx.x * 16; base < (1 << 22); base += gridDim.x * 16) {
    int seg = base + grp;
    const float4 v = *(const float4*)(x + (long)seg * 64 + sub * 4);
    float s = v.x + v.y + v.z + v.w;
    s += __shfl_xor(s, 1);
    s += __shfl_xor(s, 2);
    s += __shfl_xor(s, 4);
    s += __shfl_xor(s, 8);
    if (sub == 0) xm[seg] = f2bf(s * 0.015625f);
  }
}

// ---------------- bf16 GEMM: U[4096,1024] = xm[4096,1024] * Wb[1024,1024]^T + b ----------------
// 128x64 tile, BK=32, 4 waves as 2x2, wave tile 64x32 (4x2 frags -> 8 MFMA : 6 ds_read).
// Grid 16x32 = 512 blocks = 2 blocks/CU. global_load_lds width=16 (linear dest, rule #21);
// LDS swizzle slot ^= (r&3)^((r>>2)&3) applied identically on global source and ds_read side:
// enumeration over 16 frag rows gives perfect 2-way bank aliasing (free, m136).
#define GLDS16(g, l) \
  __builtin_amdgcn_global_load_lds((const __attribute__((address_space(1))) void*)(g), \
                                   (__attribute__((address_space(3))) void*)(l), 16, 0, 0)

__device__ __forceinline__ int swz(int r) { return (r & 3) ^ ((r >> 2) & 3); }

__global__ __launch_bounds__(256) void k_gemm(const unsigned short* __restrict__ A,
                                              const unsigned short* __restrict__ Bm,
                                              const float* __restrict__ bias,
                                              float* __restrict__ U) {
  __shared__ unsigned short As[128 * 32];  // 8 KiB
  __shared__ unsigned short Bs[64 * 32];   // 4 KiB
  const int tid  = threadIdx.x;
  const int lane = tid & 63;
  const int wid  = tid >> 6;
  const int wr = wid >> 1, wc = wid & 1;   // wave tile: rows [wr*64,+64), cols [wc*32,+32)
  const int m0 = blockIdx.y * 128, n0 = blockIdx.x * 64;

  f32x4 acc[4][2] = {};

  const int srow  = tid >> 2;  // staging row 0..63 (+64 for A round 1)
  const int sslot = tid & 3;   // physical 16B slot within 64B row
  const int r16   = lane & 15;
  const int kb    = lane >> 4;

  const unsigned short* ag0 = A  + (long)(m0 + srow) * 1024 + ((sslot ^ swz(srow)) << 3);
  const unsigned short* ag1 = A  + (long)(m0 + 64 + srow) * 1024 + ((sslot ^ swz(srow + 64)) << 3);
  const unsigned short* bg  = Bm + (long)(n0 + srow) * 1024 + ((sslot ^ swz(srow)) << 3);

  for (int k0 = 0; k0 < 1024; k0 += 32) {
    GLDS16(ag0 + k0, (char*)As + tid * 16);
    GLDS16(ag1 + k0, (char*)As + tid * 16 + 4096);
    GLDS16(bg  + k0, (char*)Bs + tid * 16);
    __syncthreads();  // compiler drains vmcnt before s_barrier

    bf16x8 af[4], bfr[2];
#pragma unroll
    for (int i = 0; i < 4; i++) {
      const int rr = wr * 64 + i * 16 + r16;
      af[i] = *(const bf16x8*)(As + rr * 32 + ((kb ^ swz(rr)) << 3));
    }
#pragma unroll
    for (int j = 0; j < 2; j++) {
      const int cc = wc * 32 + j * 16 + r16;
      bfr[j] = *(const bf16x8*)(Bs + cc * 32 + ((kb ^ swz(cc)) << 3));
    }
#pragma unroll
    for (int i = 0; i < 4; i++)
#pragma unroll
      for (int j = 0; j < 2; j++)
        acc[i][j] = __builtin_amdgcn_mfma_f32_16x16x32_bf16(af[i], bfr[j], acc[i][j], 0, 0, 0);
    __syncthreads();
  }

  // C/D layout: col = lane&15, row = (lane>>4)*4 + reg  [measured m89/m91]
  const int orow = (lane >> 4) * 4;
  const int ocol = lane & 15;
  const float bb[2] = { bias[n0 + wc * 32 + ocol], bias[n0 + wc * 32 + 16 + ocol] };
#pragma unroll
  for (int i = 0; i < 4; i++)
#pragma unroll
    for (int j = 0; j < 2; j++) {
      const int m = m0 + wr * 64 + i * 16 + orow;
      const int n = n0 + wc * 32 + j * 16 + ocol;
#pragma unroll
      for (int q = 0; q < 4; q++)
        U[(long)(m + q) * 1024 + n] = acc[i][j][q] + bb[j];
    }
}

// ---------------- diag recurrence over T, in-place in d_out ----------------
// r_t = alpha*r_{t-1} + u'_t (u' = u+b already from GEMM); r_seq overwrites u'; r_final appended.
// 256 waves total (1/CU) -> latency-bound. Software pipeline: two 64-reg buffers, issue group
// g+1's 64 independent loads before running group g's serial FMA chain. Static indexing only
// (full unroll, rule #20) so buffers stay in VGPRs.
template<int G>
__device__ __forceinline__ void scan_load(float* buf, const float* p) {
#pragma unroll
  for (int i = 0; i < 64; i++) buf[i] = p[G * 65536 + i * 1024];
}
template<int G>
__device__ __forceinline__ void scan_proc(float* buf, float* p, float a, float& r) {
#pragma unroll
  for (int i = 0; i < 64; i++) { r = fmaf(a, r, buf[i]); buf[i] = r; }
#pragma unroll
  for (int i = 0; i < 64; i++) p[G * 65536 + i * 1024] = buf[i];
}

__global__ __launch_bounds__(64) void k_scan(const float* __restrict__ r0,
                                             const float* __restrict__ alpha,
                                             float* __restrict__ out) {
  const int gid = blockIdx.x * 64 + threadIdx.x;  // 0..16383 = b*1024 + o
  const int o = gid & 1023;
  const float a = alpha[o];
  float r = r0[gid];
  float* p = out + (long)(gid >> 10) * (256L * 1024) + o;
  float bufA[64], bufB[64];
  scan_load<0>(bufA, p);
  scan_load<1>(bufB, p); scan_proc<0>(bufA, p, a, r);
  scan_load<2>(bufA, p); scan_proc<1>(bufB, p, a, r);
  scan_load<3>(bufB, p); scan_proc<2>(bufA, p, a, r);
  scan_proc<3>(bufB, p, a, r);
  out[(1 << 22) + gid] = r;  // r_final
}

extern "C" void kernel_launch(void* const* d_in, const int* in_sizes, int n_in,
                              void* d_out, int out_size, void* d_ws, size_t ws_size,
                              hipStream_t stream) {
  const float* x     = (const float*)d_in[0];
  const float* r0    = (const float*)d_in[1];
  const float* W     = (const float*)d_in[2];
  const float* b     = (const float*)d_in[3];
  const float* alpha = (const float*)d_in[4];
  float* out = (float*)d_out;

  unsigned short* xm = (unsigned short*)d_ws;                        // 8 MiB: [4096][1024] bf16
  unsigned short* Wb = (unsigned short*)((char*)d_ws + (8u << 20));  // 2 MiB: [1024][1024] bf16

  k_mean<<<2048, 256, 0, stream>>>(x, xm, W, Wb);
  dim3 g(16, 32);  // x: N-tiles (1024/64), y: M-tiles (4096/128)
  k_gemm<<<g, 256, 0, stream>>>(xm, Wb, b, out);
  k_scan<<<256, 64, 0, stream>>>(r0, alpha, out);
}